// Round 1
// baseline (2762.033 us; speedup 1.0000x reference)
//
#include <hip/hip_runtime.h>

#define F 64

// ---------------------------------------------------------------------------
// Kernel A: per-node dense init.
//   out_real[n]  = x_real[n] @ W0 + bias
//   out_imag[n]  = x_imag[n] @ W0 + bias
//   xr1[n] (ws)  = x_real[n] @ W1
//   xi1[n] (ws)  = x_imag[n] @ W1
// One wave per node row; lane = output feature. W columns live in VGPRs,
// loaded once per block (grid-stride over nodes amortizes the W fetch).
// x row loads are wave-uniform -> scalar-cache broadcast.
// ---------------------------------------------------------------------------
__global__ __launch_bounds__(256) void dihyper_gemm_init(
    const float* __restrict__ x_real, const float* __restrict__ x_imag,
    const float* __restrict__ weight, const float* __restrict__ bias,
    float* __restrict__ out_real, float* __restrict__ out_imag,
    float* __restrict__ xr1, float* __restrict__ xi1,
    int n_nodes)
{
    const int lane = threadIdx.x & 63;
    const int waveId = (blockIdx.x * blockDim.x + threadIdx.x) >> 6;
    const int nWaves = (gridDim.x * blockDim.x) >> 6;

    const float* __restrict__ W0 = weight;          // [64][64] row-major (k, f)
    const float* __restrict__ W1 = weight + F * F;

    // This lane's W columns (f = lane), held in registers for the whole block.
    float w0c[F], w1c[F];
#pragma unroll
    for (int k = 0; k < F; ++k) {
        w0c[k] = W0[k * F + lane];
        w1c[k] = W1[k * F + lane];
    }
    const float bf = bias[lane];

    for (int n = waveId; n < n_nodes; n += nWaves) {
        // n is wave-uniform; make it explicit so x-row loads use the scalar path.
        const int nu = __builtin_amdgcn_readfirstlane(n);
        const float4* __restrict__ xr4 = (const float4*)(x_real + (size_t)nu * F);
        const float4* __restrict__ xi4 = (const float4*)(x_imag + (size_t)nu * F);

        float accR0 = 0.f, accR1 = 0.f, accI0 = 0.f, accI1 = 0.f;
#pragma unroll
        for (int k4 = 0; k4 < F / 4; ++k4) {
            const float4 vr = xr4[k4];
            const float4 vi = xi4[k4];
            const float xr[4] = {vr.x, vr.y, vr.z, vr.w};
            const float xi[4] = {vi.x, vi.y, vi.z, vi.w};
#pragma unroll
            for (int j = 0; j < 4; ++j) {
                const int k = 4 * k4 + j;
                accR0 = fmaf(xr[j], w0c[k], accR0);
                accR1 = fmaf(xr[j], w1c[k], accR1);
                accI0 = fmaf(xi[j], w0c[k], accI0);
                accI1 = fmaf(xi[j], w1c[k], accI1);
            }
        }
        const size_t base = (size_t)nu * F + lane;
        out_real[base] = accR0 + bf;
        out_imag[base] = accI0 + bf;
        xr1[base]      = accR1;
        xi1[base]      = accI1;
    }
}

// ---------------------------------------------------------------------------
// Kernel B: fused complex edge scatter.
//   out_real[src] += nr * xr1[dst] - ni * xi1[dst]
//   out_imag[src] += nr * xi1[dst] + ni * xr1[dst]
// 16 threads per edge, float4 per thread (covers all 64 features).
// ---------------------------------------------------------------------------
__global__ __launch_bounds__(256) void dihyper_edge_scatter(
    const float* __restrict__ xr1, const float* __restrict__ xi1,
    const int* __restrict__ edge_index,
    const float* __restrict__ norm_real, const float* __restrict__ norm_imag,
    float* __restrict__ out_real, float* __restrict__ out_imag,
    int n_edges)
{
    const long long gid = (long long)blockIdx.x * blockDim.x + threadIdx.x;
    const long long total = (long long)n_edges * 16;
    if (gid >= total) return;

    const int e = (int)(gid >> 4);
    const int c = (int)(gid & 15);          // float4 chunk within the 64 feats

    const int s = edge_index[e];            // aggregation target
    const int d = edge_index[n_edges + e];  // gathered neighbor
    const float cr = norm_real[e];
    const float ci = norm_imag[e];

    const size_t goff = (size_t)d * F + c * 4;
    const float4 ar = *(const float4*)(xr1 + goff);
    const float4 ai = *(const float4*)(xi1 + goff);

    float* __restrict__ pr = out_real + (size_t)s * F + c * 4;
    float* __restrict__ pi = out_imag + (size_t)s * F + c * 4;

    unsafeAtomicAdd(pr + 0, fmaf(cr, ar.x, -ci * ai.x));
    unsafeAtomicAdd(pr + 1, fmaf(cr, ar.y, -ci * ai.y));
    unsafeAtomicAdd(pr + 2, fmaf(cr, ar.z, -ci * ai.z));
    unsafeAtomicAdd(pr + 3, fmaf(cr, ar.w, -ci * ai.w));

    unsafeAtomicAdd(pi + 0, fmaf(cr, ai.x, ci * ar.x));
    unsafeAtomicAdd(pi + 1, fmaf(cr, ai.y, ci * ar.y));
    unsafeAtomicAdd(pi + 2, fmaf(cr, ai.z, ci * ar.z));
    unsafeAtomicAdd(pi + 3, fmaf(cr, ai.w, ci * ar.w));
}

extern "C" void kernel_launch(void* const* d_in, const int* in_sizes, int n_in,
                              void* d_out, int out_size, void* d_ws, size_t ws_size,
                              hipStream_t stream) {
    const float* x_real    = (const float*)d_in[0];
    const float* x_imag    = (const float*)d_in[1];
    const float* weight    = (const float*)d_in[2];   // (2, 64, 64)
    const float* bias      = (const float*)d_in[3];   // (64,)
    const float* norm_real = (const float*)d_in[4];   // (E,)
    const float* norm_imag = (const float*)d_in[5];   // (E,)
    const int*   edge_index = (const int*)d_in[6];    // (2, E)

    const int n_nodes = in_sizes[0] / F;
    const int n_edges = in_sizes[4];

    float* out_real = (float*)d_out;
    float* out_imag = out_real + (size_t)n_nodes * F;

    float* xr1 = (float*)d_ws;                       // n_nodes * 64 f32
    float* xi1 = xr1 + (size_t)n_nodes * F;          // n_nodes * 64 f32

    dihyper_gemm_init<<<2048, 256, 0, stream>>>(
        x_real, x_imag, weight, bias, out_real, out_imag, xr1, xi1, n_nodes);

    const long long work = (long long)n_edges * 16;
    const int blocks = (int)((work + 255) / 256);
    dihyper_edge_scatter<<<blocks, 256, 0, stream>>>(
        xr1, xi1, edge_index, norm_real, norm_imag, out_real, out_imag, n_edges);
}

// Round 2
// 657.616 us; speedup vs baseline: 4.2001x; 4.2001x over previous
//
#include <hip/hip_runtime.h>

#define F 64

// ---------------------------------------------------------------------------
// Kernel A: per-node dense init.
//   out_real[n] = x_real[n] @ W0 + bias ; out_imag[n] = x_imag[n] @ W0 + bias
//   x1[n][0][:] = x_real[n] @ W1        ; x1[n][1][:] = x_imag[n] @ W1
// One wave per node; lane = output feature; W columns in VGPRs.
// ---------------------------------------------------------------------------
__global__ __launch_bounds__(256) void dihyper_gemm_init(
    const float* __restrict__ x_real, const float* __restrict__ x_imag,
    const float* __restrict__ weight, const float* __restrict__ bias,
    float* __restrict__ out_real, float* __restrict__ out_imag,
    float* __restrict__ x1,            // interleaved [n][2][64]
    int n_nodes)
{
    const int lane = threadIdx.x & 63;
    const int waveId = (blockIdx.x * blockDim.x + threadIdx.x) >> 6;
    const int nWaves = (gridDim.x * blockDim.x) >> 6;

    const float* __restrict__ W0 = weight;
    const float* __restrict__ W1 = weight + F * F;

    float w0c[F], w1c[F];
#pragma unroll
    for (int k = 0; k < F; ++k) {
        w0c[k] = W0[k * F + lane];
        w1c[k] = W1[k * F + lane];
    }
    const float bf = bias[lane];

    for (int n = waveId; n < n_nodes; n += nWaves) {
        const int nu = __builtin_amdgcn_readfirstlane(n);
        const float4* __restrict__ xr4 = (const float4*)(x_real + (size_t)nu * F);
        const float4* __restrict__ xi4 = (const float4*)(x_imag + (size_t)nu * F);

        float accR0 = 0.f, accR1 = 0.f, accI0 = 0.f, accI1 = 0.f;
#pragma unroll
        for (int k4 = 0; k4 < F / 4; ++k4) {
            const float4 vr = xr4[k4];
            const float4 vi = xi4[k4];
            const float xr[4] = {vr.x, vr.y, vr.z, vr.w};
            const float xi[4] = {vi.x, vi.y, vi.z, vi.w};
#pragma unroll
            for (int j = 0; j < 4; ++j) {
                const int k = 4 * k4 + j;
                accR0 = fmaf(xr[j], w0c[k], accR0);
                accR1 = fmaf(xr[j], w1c[k], accR1);
                accI0 = fmaf(xi[j], w0c[k], accI0);
                accI1 = fmaf(xi[j], w1c[k], accI1);
            }
        }
        const size_t base = (size_t)nu * F + lane;
        out_real[base] = accR0 + bf;
        out_imag[base] = accI0 + bf;
        x1[(size_t)nu * (2 * F) + lane]     = accR1;
        x1[(size_t)nu * (2 * F) + F + lane] = accI1;
    }
}

// ---------------------------------------------------------------------------
// CSR build: zero -> histogram -> scan -> placement
// ---------------------------------------------------------------------------
__global__ void k_zero(int* __restrict__ p, int n) {
    int i = blockIdx.x * 256 + threadIdx.x;
    if (i < n) p[i] = 0;
}

__global__ void k_hist(const int* __restrict__ src, int* __restrict__ counts, int n_edges) {
    int e = blockIdx.x * 256 + threadIdx.x;
    if (e < n_edges) atomicAdd(&counts[src[e]], 1);
}

// Single-block exclusive scan over n counts (8 elems/thread, 1024 threads).
// In: cnt_cur holds counts. Out: offsets[0..n] exclusive scan; cnt_cur[i] = offsets[i] (cursor copy).
__global__ __launch_bounds__(1024) void k_scan(int* __restrict__ cnt_cur, int* __restrict__ offsets, int n) {
    __shared__ int sdata[1024];
    __shared__ int s_carry;
    const int t = threadIdx.x;
    if (t == 0) s_carry = 0;
    __syncthreads();
    for (int base = 0; base < n; base += 1024 * 8) {
        int v[8];
        int local = 0;
        const int idx0 = base + t * 8;
#pragma unroll
        for (int j = 0; j < 8; ++j) {
            const int idx = idx0 + j;
            const int c = (idx < n) ? cnt_cur[idx] : 0;
            v[j] = local;           // exclusive within thread
            local += c;
        }
        sdata[t] = local;
        __syncthreads();
        for (int off = 1; off < 1024; off <<= 1) {
            const int x = (t >= off) ? sdata[t - off] : 0;
            __syncthreads();
            sdata[t] += x;
            __syncthreads();
        }
        const int texcl = s_carry + (t ? sdata[t - 1] : 0);
        const int ctot  = s_carry + sdata[1023];
        __syncthreads();            // everyone done reading s_carry/sdata
#pragma unroll
        for (int j = 0; j < 8; ++j) {
            const int idx = idx0 + j;
            if (idx < n) {
                const int o = texcl + v[j];
                offsets[idx] = o;
                cnt_cur[idx] = o;   // cursor for placement
            }
        }
        if (t == 0) s_carry = ctot;
        __syncthreads();
    }
    if (t == 0) offsets[n] = s_carry;
}

__global__ void k_place(const int* __restrict__ src, int* __restrict__ cursor,
                        int* __restrict__ eid, int n_edges) {
    int e = blockIdx.x * 256 + threadIdx.x;
    if (e >= n_edges) return;
    const int pos = atomicAdd(&cursor[src[e]], 1);
    eid[pos] = e;
}

// ---------------------------------------------------------------------------
// Gather: one wave per node, no float atomics.
//   out_real[n] += sum_e  nr*xr1[dst] - ni*xi1[dst]
//   out_imag[n] += sum_e  nr*xi1[dst] + ni*xr1[dst]
// ---------------------------------------------------------------------------
__global__ __launch_bounds__(256) void dihyper_gather(
    const float* __restrict__ x1,      // [n][2][64]
    const int* __restrict__ dst,       // edge_index + E
    const float* __restrict__ nr_, const float* __restrict__ ni_,
    const int* __restrict__ offsets, const int* __restrict__ eid,
    float* __restrict__ out_real, float* __restrict__ out_imag,
    int n_nodes)
{
    const int lane = threadIdx.x & 63;
    const int w = (blockIdx.x * blockDim.x + threadIdx.x) >> 6;
    const int nw = (gridDim.x * blockDim.x) >> 6;

    for (int n = w; n < n_nodes; n += nw) {
        const int beg = __builtin_amdgcn_readfirstlane(offsets[n]);
        const int end = __builtin_amdgcn_readfirstlane(offsets[n + 1]);

        float aR0 = 0.f, aI0 = 0.f, aR1 = 0.f, aI1 = 0.f;
        int e = beg;
        for (; e + 1 < end; e += 2) {
            const int e0 = eid[e], e1 = eid[e + 1];
            const int d0 = dst[e0], d1 = dst[e1];
            const float nr0 = nr_[e0], ni0 = ni_[e0];
            const float nr1 = nr_[e1], ni1 = ni_[e1];
            const float* __restrict__ r0 = x1 + (size_t)d0 * (2 * F);
            const float* __restrict__ r1 = x1 + (size_t)d1 * (2 * F);
            const float xr0 = r0[lane],     xi0 = r0[F + lane];
            const float xr1v = r1[lane],    xi1v = r1[F + lane];
            aR0 = fmaf(nr0, xr0,  fmaf(-ni0, xi0,  aR0));
            aI0 = fmaf(nr0, xi0,  fmaf( ni0, xr0,  aI0));
            aR1 = fmaf(nr1, xr1v, fmaf(-ni1, xi1v, aR1));
            aI1 = fmaf(nr1, xi1v, fmaf( ni1, xr1v, aI1));
        }
        if (e < end) {
            const int e0 = eid[e];
            const int d0 = dst[e0];
            const float nr0 = nr_[e0], ni0 = ni_[e0];
            const float* __restrict__ r0 = x1 + (size_t)d0 * (2 * F);
            const float xr0 = r0[lane], xi0 = r0[F + lane];
            aR0 = fmaf(nr0, xr0, fmaf(-ni0, xi0, aR0));
            aI0 = fmaf(nr0, xi0, fmaf( ni0, xr0, aI0));
        }
        const size_t b = (size_t)n * F + lane;
        out_real[b] += aR0 + aR1;
        out_imag[b] += aI0 + aI1;
    }
}

// ---------------------------------------------------------------------------
// Fallback (ws too small): round-1 atomic scatter, interleaved x1 layout.
// ---------------------------------------------------------------------------
__global__ __launch_bounds__(256) void dihyper_edge_scatter(
    const float* __restrict__ x1,
    const int* __restrict__ edge_index,
    const float* __restrict__ norm_real, const float* __restrict__ norm_imag,
    float* __restrict__ out_real, float* __restrict__ out_imag,
    int n_edges)
{
    const long long gid = (long long)blockIdx.x * blockDim.x + threadIdx.x;
    const long long total = (long long)n_edges * 16;
    if (gid >= total) return;

    const int e = (int)(gid >> 4);
    const int c = (int)(gid & 15);

    const int s = edge_index[e];
    const int d = edge_index[n_edges + e];
    const float cr = norm_real[e];
    const float ci = norm_imag[e];

    const float* __restrict__ row = x1 + (size_t)d * (2 * F);
    const float4 ar = *(const float4*)(row + c * 4);
    const float4 ai = *(const float4*)(row + F + c * 4);

    float* __restrict__ pr = out_real + (size_t)s * F + c * 4;
    float* __restrict__ pi = out_imag + (size_t)s * F + c * 4;

    unsafeAtomicAdd(pr + 0, fmaf(cr, ar.x, -ci * ai.x));
    unsafeAtomicAdd(pr + 1, fmaf(cr, ar.y, -ci * ai.y));
    unsafeAtomicAdd(pr + 2, fmaf(cr, ar.z, -ci * ai.z));
    unsafeAtomicAdd(pr + 3, fmaf(cr, ar.w, -ci * ai.w));
    unsafeAtomicAdd(pi + 0, fmaf(cr, ai.x, ci * ar.x));
    unsafeAtomicAdd(pi + 1, fmaf(cr, ai.y, ci * ar.y));
    unsafeAtomicAdd(pi + 2, fmaf(cr, ai.z, ci * ar.z));
    unsafeAtomicAdd(pi + 3, fmaf(cr, ai.w, ci * ar.w));
}

extern "C" void kernel_launch(void* const* d_in, const int* in_sizes, int n_in,
                              void* d_out, int out_size, void* d_ws, size_t ws_size,
                              hipStream_t stream) {
    const float* x_real     = (const float*)d_in[0];
    const float* x_imag     = (const float*)d_in[1];
    const float* weight     = (const float*)d_in[2];
    const float* bias       = (const float*)d_in[3];
    const float* norm_real  = (const float*)d_in[4];
    const float* norm_imag  = (const float*)d_in[5];
    const int*   edge_index = (const int*)d_in[6];

    const int n_nodes = in_sizes[0] / F;
    const int n_edges = in_sizes[4];

    float* out_real = (float*)d_out;
    float* out_imag = out_real + (size_t)n_nodes * F;

    // ws layout
    char* ws = (char*)d_ws;
    const size_t x1_bytes  = (size_t)n_nodes * 2 * F * sizeof(float);
    const size_t off_bytes = (size_t)(n_nodes + 1) * sizeof(int);
    const size_t cur_bytes = (size_t)n_nodes * sizeof(int);
    const size_t eid_bytes = (size_t)n_edges * sizeof(int);
    const size_t need = x1_bytes + off_bytes + cur_bytes + eid_bytes;

    float* x1      = (float*)ws;
    int*   offsets = (int*)(ws + x1_bytes);
    int*   cursor  = (int*)(ws + x1_bytes + off_bytes);
    int*   eid     = (int*)(ws + x1_bytes + off_bytes + cur_bytes);

    // Kernel A: out = x@W0 + bias ; x1 = x@W1 (interleaved)
    dihyper_gemm_init<<<2048, 256, 0, stream>>>(
        x_real, x_imag, weight, bias, out_real, out_imag, x1, n_nodes);

    const int eblocks = (n_edges + 255) / 256;

    if (ws_size >= need) {
        // CSR build
        k_zero<<<(n_nodes + 255) / 256, 256, 0, stream>>>(cursor, n_nodes);
        k_hist<<<eblocks, 256, 0, stream>>>(edge_index, cursor, n_edges);
        k_scan<<<1, 1024, 0, stream>>>(cursor, offsets, n_nodes);
        k_place<<<eblocks, 256, 0, stream>>>(edge_index, cursor, eid, n_edges);

        // Gather: one wave per node
        const int gblocks = (n_nodes + 3) / 4;   // 4 waves per 256-thread block
        dihyper_gather<<<gblocks, 256, 0, stream>>>(
            x1, edge_index + n_edges, norm_real, norm_imag,
            offsets, eid, out_real, out_imag, n_nodes);
    } else {
        // Fallback: atomic scatter (requires only x1 in ws)
        const long long work = (long long)n_edges * 16;
        const int blocks = (int)((work + 255) / 256);
        dihyper_edge_scatter<<<blocks, 256, 0, stream>>>(
            x1, edge_index, norm_real, norm_imag, out_real, out_imag, n_edges);
    }
}

// Round 3
// 608.869 us; speedup vs baseline: 4.5363x; 1.0801x over previous
//
#include <hip/hip_runtime.h>

#define F 64
typedef unsigned int u32;

// ---- bf16x2 pack/unpack (RNE) ----------------------------------------------
__device__ __forceinline__ u32 pack_bf16x2(float lo, float hi) {
    u32 a = __float_as_uint(lo);
    u32 b = __float_as_uint(hi);
    a = (a + 0x7fffu + ((a >> 16) & 1u)) >> 16;
    b = (b + 0x7fffu + ((b >> 16) & 1u)) >> 16;
    return a | (b << 16);
}
__device__ __forceinline__ float unpack_lo(u32 p) { return __uint_as_float(p << 16); }
__device__ __forceinline__ float unpack_hi(u32 p) { return __uint_as_float(p & 0xffff0000u); }

// ---------------------------------------------------------------------------
// Kernel A: x1p[n][f] = pack_bf16( x_real[n]@W1 [f], x_imag[n]@W1 [f] )
// One wave per node; lane = feature; W1 columns in VGPRs.
// ---------------------------------------------------------------------------
__global__ __launch_bounds__(256) void k_x1(
    const float* __restrict__ x_real, const float* __restrict__ x_imag,
    const float* __restrict__ weight, u32* __restrict__ x1p, int n_nodes)
{
    const int lane = threadIdx.x & 63;
    const int waveId = (blockIdx.x * blockDim.x + threadIdx.x) >> 6;
    const int nWaves = (gridDim.x * blockDim.x) >> 6;

    const float* __restrict__ W1 = weight + F * F;
    float w1c[F];
#pragma unroll
    for (int k = 0; k < F; ++k) w1c[k] = W1[k * F + lane];

    for (int n = waveId; n < n_nodes; n += nWaves) {
        const int nu = __builtin_amdgcn_readfirstlane(n);
        const float4* __restrict__ xr4 = (const float4*)(x_real + (size_t)nu * F);
        const float4* __restrict__ xi4 = (const float4*)(x_imag + (size_t)nu * F);
        float aR = 0.f, aI = 0.f;
#pragma unroll
        for (int k4 = 0; k4 < F / 4; ++k4) {
            const float4 vr = xr4[k4];
            const float4 vi = xi4[k4];
            const float xr[4] = {vr.x, vr.y, vr.z, vr.w};
            const float xi[4] = {vi.x, vi.y, vi.z, vi.w};
#pragma unroll
            for (int j = 0; j < 4; ++j) {
                const int k = 4 * k4 + j;
                aR = fmaf(xr[j], w1c[k], aR);
                aI = fmaf(xi[j], w1c[k], aI);
            }
        }
        x1p[(size_t)nu * F + lane] = pack_bf16x2(aR, aI);
    }
}

// ---------------------------------------------------------------------------
// CSR build
// ---------------------------------------------------------------------------
__global__ void k_hist(const int* __restrict__ src, int* __restrict__ counts, int n_edges) {
    int e = blockIdx.x * 256 + threadIdx.x;
    if (e < n_edges) atomicAdd(&counts[src[e]], 1);
}

// Single-pass block scan: 1024 threads, contiguous chunk per thread,
// wave shuffle-scan + 16 wave sums. In: cnt=counts. Out: offsets (exclusive,
// n+1) and cnt rewritten as cursor (= offsets[i]).
__global__ __launch_bounds__(1024) void k_scan(int* __restrict__ cnt, int* __restrict__ offsets, int n) {
    __shared__ int wsum[16];
    const int t = threadIdx.x;
    const int lane = t & 63, wid = t >> 6;
    const int chunk = (n + 1023) >> 10;
    const int beg = t * chunk;
    const int end = min(beg + chunk, n);

    int local = 0;
    for (int i = beg; i < end; ++i) local += cnt[i];

    int incl = local;
#pragma unroll
    for (int d = 1; d < 64; d <<= 1) {
        int v = __shfl_up(incl, d);
        if (lane >= d) incl += v;
    }
    if (lane == 63) wsum[wid] = incl;
    __syncthreads();
    if (wid == 0) {
        int s = (lane < 16) ? wsum[lane] : 0;
#pragma unroll
        for (int d = 1; d < 16; d <<= 1) {
            int v = __shfl_up(s, d);
            if (lane >= d) s += v;
        }
        if (lane < 16) wsum[lane] = s;
    }
    __syncthreads();

    int run = incl - local + (wid ? wsum[wid - 1] : 0);  // exclusive prefix
    for (int i = beg; i < end; ++i) {
        const int c = cnt[i];
        offsets[i] = run;
        cnt[i] = run;
        run += c;
    }
    if (t == 1023) offsets[n] = run;
}

// Placement: meta[pos] = {dst, 0, nr, ni} sorted by src.
__global__ void k_place(const int* __restrict__ edge_index,
                        const float* __restrict__ nr, const float* __restrict__ ni,
                        int* __restrict__ cursor, int4* __restrict__ meta, int n_edges) {
    int e = blockIdx.x * 256 + threadIdx.x;
    if (e >= n_edges) return;
    const int s = edge_index[e];
    const int pos = atomicAdd(&cursor[s], 1);
    int4 m;
    m.x = edge_index[n_edges + e];
    m.y = 0;
    m.z = __float_as_int(nr[e]);
    m.w = __float_as_int(ni[e]);
    meta[pos] = m;
}

// ---------------------------------------------------------------------------
// Fused gather: one wave per node.
//   out_real[n] = x_real[n]@W0 + b + sum_e (nr*xr1[dst] - ni*xi1[dst])
//   out_imag[n] = x_imag[n]@W0 + b + sum_e (nr*xi1[dst] + ni*xr1[dst])
// ---------------------------------------------------------------------------
#define APPLY(m, p, aR, aI)                                   \
    do {                                                      \
        const float cr = __int_as_float((m).z);               \
        const float ci = __int_as_float((m).w);               \
        const float xr = unpack_lo(p);                        \
        const float xi = unpack_hi(p);                        \
        aR = fmaf(cr, xr, fmaf(-ci, xi, aR));                 \
        aI = fmaf(cr, xi, fmaf(ci, xr, aI));                  \
    } while (0)

__global__ __launch_bounds__(256) void k_gather(
    const u32* __restrict__ x1p,
    const float* __restrict__ x_real, const float* __restrict__ x_imag,
    const float* __restrict__ weight, const float* __restrict__ bias,
    const int* __restrict__ offsets, const int4* __restrict__ meta,
    float* __restrict__ out_real, float* __restrict__ out_imag,
    int n_nodes)
{
    const int lane = threadIdx.x & 63;
    const int w = (blockIdx.x * blockDim.x + threadIdx.x) >> 6;
    const int nw = (gridDim.x * blockDim.x) >> 6;

    const float* __restrict__ W0 = weight;
    float w0c[F];
#pragma unroll
    for (int k = 0; k < F; ++k) w0c[k] = W0[k * F + lane];
    const float bf = bias[lane];

    for (int n = w; n < n_nodes; n += nw) {
        const int nu = __builtin_amdgcn_readfirstlane(n);
        const int beg = __builtin_amdgcn_readfirstlane(offsets[nu]);
        const int end = __builtin_amdgcn_readfirstlane(offsets[nu + 1]);

        float aR0 = 0.f, aI0 = 0.f, aR1 = 0.f, aI1 = 0.f;
        float aR2 = 0.f, aI2 = 0.f, aR3 = 0.f, aI3 = 0.f;

        int e = beg;
        for (; e + 4 <= end; e += 4) {
            const int4 m0 = meta[e + 0];
            const int4 m1 = meta[e + 1];
            const int4 m2 = meta[e + 2];
            const int4 m3 = meta[e + 3];
            const u32 p0 = x1p[(size_t)m0.x * F + lane];
            const u32 p1 = x1p[(size_t)m1.x * F + lane];
            const u32 p2 = x1p[(size_t)m2.x * F + lane];
            const u32 p3 = x1p[(size_t)m3.x * F + lane];
            APPLY(m0, p0, aR0, aI0);
            APPLY(m1, p1, aR1, aI1);
            APPLY(m2, p2, aR2, aI2);
            APPLY(m3, p3, aR3, aI3);
        }
        for (; e < end; ++e) {
            const int4 m = meta[e];
            const u32 p = x1p[(size_t)m.x * F + lane];
            APPLY(m, p, aR0, aI0);
        }

        // Fused x@W0 (both real and imag rows).
        const float4* __restrict__ xr4 = (const float4*)(x_real + (size_t)nu * F);
        const float4* __restrict__ xi4 = (const float4*)(x_imag + (size_t)nu * F);
        float gR = 0.f, gI = 0.f;
#pragma unroll
        for (int k4 = 0; k4 < F / 4; ++k4) {
            const float4 vr = xr4[k4];
            const float4 vi = xi4[k4];
            const float xr[4] = {vr.x, vr.y, vr.z, vr.w};
            const float xi[4] = {vi.x, vi.y, vi.z, vi.w};
#pragma unroll
            for (int j = 0; j < 4; ++j) {
                const int k = 4 * k4 + j;
                gR = fmaf(xr[j], w0c[k], gR);
                gI = fmaf(xi[j], w0c[k], gI);
            }
        }

        const size_t b = (size_t)nu * F + lane;
        out_real[b] = gR + bf + ((aR0 + aR1) + (aR2 + aR3));
        out_imag[b] = gI + bf + ((aI0 + aI1) + (aI2 + aI3));
    }
}

// ---------------------------------------------------------------------------
// Fallback (ws too small): atomic scatter from packed x1 + separate init.
// ---------------------------------------------------------------------------
__global__ __launch_bounds__(256) void k_init_out(
    const float* __restrict__ x_real, const float* __restrict__ x_imag,
    const float* __restrict__ weight, const float* __restrict__ bias,
    float* __restrict__ out_real, float* __restrict__ out_imag, int n_nodes)
{
    const int lane = threadIdx.x & 63;
    const int waveId = (blockIdx.x * blockDim.x + threadIdx.x) >> 6;
    const int nWaves = (gridDim.x * blockDim.x) >> 6;
    const float* __restrict__ W0 = weight;
    float w0c[F];
#pragma unroll
    for (int k = 0; k < F; ++k) w0c[k] = W0[k * F + lane];
    const float bf = bias[lane];
    for (int n = waveId; n < n_nodes; n += nWaves) {
        const int nu = __builtin_amdgcn_readfirstlane(n);
        const float4* __restrict__ xr4 = (const float4*)(x_real + (size_t)nu * F);
        const float4* __restrict__ xi4 = (const float4*)(x_imag + (size_t)nu * F);
        float gR = 0.f, gI = 0.f;
#pragma unroll
        for (int k4 = 0; k4 < F / 4; ++k4) {
            const float4 vr = xr4[k4];
            const float4 vi = xi4[k4];
            const float xr[4] = {vr.x, vr.y, vr.z, vr.w};
            const float xi[4] = {vi.x, vi.y, vi.z, vi.w};
#pragma unroll
            for (int j = 0; j < 4; ++j) {
                const int k = 4 * k4 + j;
                gR = fmaf(xr[j], w0c[k], gR);
                gI = fmaf(xi[j], w0c[k], gI);
            }
        }
        const size_t b = (size_t)nu * F + lane;
        out_real[b] = gR + bf;
        out_imag[b] = gI + bf;
    }
}

__global__ __launch_bounds__(256) void k_scatter(
    const u32* __restrict__ x1p, const int* __restrict__ edge_index,
    const float* __restrict__ norm_real, const float* __restrict__ norm_imag,
    float* __restrict__ out_real, float* __restrict__ out_imag, int n_edges)
{
    const long long gid = (long long)blockIdx.x * blockDim.x + threadIdx.x;
    const long long total = (long long)n_edges * 16;
    if (gid >= total) return;
    const int e = (int)(gid >> 4);
    const int c = (int)(gid & 15);
    const int s = edge_index[e];
    const int d = edge_index[n_edges + e];
    const float cr = norm_real[e];
    const float ci = norm_imag[e];
    const uint4 p4 = *(const uint4*)(x1p + (size_t)d * F + c * 4);
    const u32 pp[4] = {p4.x, p4.y, p4.z, p4.w};
    float* __restrict__ pr = out_real + (size_t)s * F + c * 4;
    float* __restrict__ pi = out_imag + (size_t)s * F + c * 4;
#pragma unroll
    for (int j = 0; j < 4; ++j) {
        const float xr = unpack_lo(pp[j]);
        const float xi = unpack_hi(pp[j]);
        unsafeAtomicAdd(pr + j, fmaf(cr, xr, -ci * xi));
        unsafeAtomicAdd(pi + j, fmaf(cr, xi, ci * xr));
    }
}

extern "C" void kernel_launch(void* const* d_in, const int* in_sizes, int n_in,
                              void* d_out, int out_size, void* d_ws, size_t ws_size,
                              hipStream_t stream) {
    const float* x_real     = (const float*)d_in[0];
    const float* x_imag     = (const float*)d_in[1];
    const float* weight     = (const float*)d_in[2];
    const float* bias       = (const float*)d_in[3];
    const float* norm_real  = (const float*)d_in[4];
    const float* norm_imag  = (const float*)d_in[5];
    const int*   edge_index = (const int*)d_in[6];

    const int n_nodes = in_sizes[0] / F;
    const int n_edges = in_sizes[4];

    float* out_real = (float*)d_out;
    float* out_imag = out_real + (size_t)n_nodes * F;

    // ws layout: [x1p][meta][offsets][cursor]
    char* ws = (char*)d_ws;
    const size_t x1_bytes   = (size_t)n_nodes * F * sizeof(u32);     // 25.6 MB
    const size_t meta_bytes = (size_t)n_edges * sizeof(int4);        // 25.6 MB
    const size_t off_bytes  = (size_t)(n_nodes + 1) * sizeof(int);
    const size_t cur_bytes  = (size_t)n_nodes * sizeof(int);
    const size_t need = x1_bytes + meta_bytes + off_bytes + cur_bytes;

    u32*  x1p     = (u32*)ws;
    int4* meta    = (int4*)(ws + x1_bytes);
    int*  offsets = (int*)(ws + x1_bytes + meta_bytes);
    int*  cursor  = (int*)(ws + x1_bytes + meta_bytes + off_bytes);

    k_x1<<<2048, 256, 0, stream>>>(x_real, x_imag, weight, x1p, n_nodes);

    const int eblocks = (n_edges + 255) / 256;

    if (ws_size >= need) {
        hipMemsetAsync(cursor, 0, cur_bytes, stream);
        k_hist<<<eblocks, 256, 0, stream>>>(edge_index, cursor, n_edges);
        k_scan<<<1, 1024, 0, stream>>>(cursor, offsets, n_nodes);
        k_place<<<eblocks, 256, 0, stream>>>(edge_index, norm_real, norm_imag,
                                             cursor, meta, n_edges);
        k_gather<<<2048, 256, 0, stream>>>(
            x1p, x_real, x_imag, weight, bias, offsets, meta,
            out_real, out_imag, n_nodes);
    } else {
        k_init_out<<<2048, 256, 0, stream>>>(
            x_real, x_imag, weight, bias, out_real, out_imag, n_nodes);
        const long long work = (long long)n_edges * 16;
        const int blocks = (int)((work + 255) / 256);
        k_scatter<<<blocks, 256, 0, stream>>>(
            x1p, edge_index, norm_real, norm_imag, out_real, out_imag, n_edges);
    }
}

// Round 4
// 395.582 us; speedup vs baseline: 6.9822x; 1.5392x over previous
//
#include <hip/hip_runtime.h>

#define F 64
typedef unsigned int u32;

#define SCAN_BLOCK 1024
#define SCAN_ITEMS 4   // elements per thread -> 4096 per block

// ---- bf16x2 pack/unpack (RNE) ----------------------------------------------
__device__ __forceinline__ u32 pack_bf16x2(float lo, float hi) {
    u32 a = __float_as_uint(lo);
    u32 b = __float_as_uint(hi);
    a = (a + 0x7fffu + ((a >> 16) & 1u)) >> 16;
    b = (b + 0x7fffu + ((b >> 16) & 1u)) >> 16;
    return a | (b << 16);
}
__device__ __forceinline__ float unpack_lo(u32 p) { return __uint_as_float(p << 16); }
__device__ __forceinline__ float unpack_hi(u32 p) { return __uint_as_float(p & 0xffff0000u); }

// ---------------------------------------------------------------------------
// Kernel A: x1p[n][f] = pack_bf16( x_real[n]@W1 [f], x_imag[n]@W1 [f] )
// ---------------------------------------------------------------------------
__global__ __launch_bounds__(256) void k_x1(
    const float* __restrict__ x_real, const float* __restrict__ x_imag,
    const float* __restrict__ weight, u32* __restrict__ x1p, int n_nodes)
{
    const int lane = threadIdx.x & 63;
    const int waveId = (blockIdx.x * blockDim.x + threadIdx.x) >> 6;
    const int nWaves = (gridDim.x * blockDim.x) >> 6;

    const float* __restrict__ W1 = weight + F * F;
    float w1c[F];
#pragma unroll
    for (int k = 0; k < F; ++k) w1c[k] = W1[k * F + lane];

    for (int n = waveId; n < n_nodes; n += nWaves) {
        const int nu = __builtin_amdgcn_readfirstlane(n);
        const float4* __restrict__ xr4 = (const float4*)(x_real + (size_t)nu * F);
        const float4* __restrict__ xi4 = (const float4*)(x_imag + (size_t)nu * F);
        float aR = 0.f, aI = 0.f;
#pragma unroll
        for (int k4 = 0; k4 < F / 4; ++k4) {
            const float4 vr = xr4[k4];
            const float4 vi = xi4[k4];
            const float xr[4] = {vr.x, vr.y, vr.z, vr.w};
            const float xi[4] = {vi.x, vi.y, vi.z, vi.w};
#pragma unroll
            for (int j = 0; j < 4; ++j) {
                const int k = 4 * k4 + j;
                aR = fmaf(xr[j], w1c[k], aR);
                aI = fmaf(xi[j], w1c[k], aI);
            }
        }
        x1p[(size_t)nu * F + lane] = pack_bf16x2(aR, aI);
    }
}

// ---------------------------------------------------------------------------
// CSR build
// ---------------------------------------------------------------------------
__global__ void k_hist(const int* __restrict__ src, int* __restrict__ counts, int n_edges) {
    int e = blockIdx.x * 256 + threadIdx.x;
    if (e < n_edges) atomicAdd(&counts[src[e]], 1);
}

// Pass 1: per-block exclusive prefix (in-block) -> pre[], block totals -> partials[].
__global__ __launch_bounds__(1024) void k_scan1(
    const int* __restrict__ cnt, int* __restrict__ pre,
    int* __restrict__ partials, int n)
{
    __shared__ int wsum[16];
    const int t = threadIdx.x;
    const int lane = t & 63, wid = t >> 6;
    const int base = blockIdx.x * (SCAN_BLOCK * SCAN_ITEMS) + t * SCAN_ITEMS;

    int v[SCAN_ITEMS];
    int local = 0;
#pragma unroll
    for (int j = 0; j < SCAN_ITEMS; ++j) {
        const int idx = base + j;
        const int c = (idx < n) ? cnt[idx] : 0;
        v[j] = local;          // exclusive within thread
        local += c;
    }
    int incl = local;
#pragma unroll
    for (int d = 1; d < 64; d <<= 1) {
        int x = __shfl_up(incl, d);
        if (lane >= d) incl += x;
    }
    if (lane == 63) wsum[wid] = incl;
    __syncthreads();
    if (wid == 0) {
        int s = (lane < 16) ? wsum[lane] : 0;
#pragma unroll
        for (int d = 1; d < 16; d <<= 1) {
            int x = __shfl_up(s, d);
            if (lane >= d) s += x;
        }
        if (lane < 16) wsum[lane] = s;
    }
    __syncthreads();
    const int texcl = (incl - local) + (wid ? wsum[wid - 1] : 0);
#pragma unroll
    for (int j = 0; j < SCAN_ITEMS; ++j) {
        const int idx = base + j;
        if (idx < n) pre[idx] = texcl + v[j];
    }
    if (t == SCAN_BLOCK - 1) partials[blockIdx.x] = texcl + local;
}

// Pass 2: add block offset; write final offsets + cursor. Assumes gridDim <= 64.
__global__ __launch_bounds__(1024) void k_scan2(
    int* __restrict__ pre /* = offsets, in-place */, const int* __restrict__ partials,
    int* __restrict__ cursor, int n, int n_edges)
{
    __shared__ int s_off;
    const int t = threadIdx.x;
    if (t < 64) {
        int val = (t < blockIdx.x) ? partials[t] : 0;
#pragma unroll
        for (int d = 32; d > 0; d >>= 1) val += __shfl_down(val, d);
        if (t == 0) s_off = val;
    }
    __syncthreads();
    const int boff = s_off;
    const int base = blockIdx.x * (SCAN_BLOCK * SCAN_ITEMS) + t * SCAN_ITEMS;
#pragma unroll
    for (int j = 0; j < SCAN_ITEMS; ++j) {
        const int idx = base + j;
        if (idx < n) {
            const int o = boff + pre[idx];
            pre[idx] = o;       // final exclusive offset
            cursor[idx] = o;    // placement cursor
        }
    }
    if (blockIdx.x == 0 && t == 0) pre[n] = n_edges;
}

// Placement: meta[pos] = {dst, 0, nr, ni} sorted by src.
__global__ void k_place(const int* __restrict__ edge_index,
                        const float* __restrict__ nr, const float* __restrict__ ni,
                        int* __restrict__ cursor, int4* __restrict__ meta, int n_edges) {
    int e = blockIdx.x * 256 + threadIdx.x;
    if (e >= n_edges) return;
    const int s = edge_index[e];
    const int pos = atomicAdd(&cursor[s], 1);
    int4 m;
    m.x = edge_index[n_edges + e];
    m.y = 0;
    m.z = __float_as_int(nr[e]);
    m.w = __float_as_int(ni[e]);
    meta[pos] = m;
}

// ---------------------------------------------------------------------------
// Fused gather: one wave per node.
// ---------------------------------------------------------------------------
#define APPLY(m, p, aR, aI)                                   \
    do {                                                      \
        const float cr = __int_as_float((m).z);               \
        const float ci = __int_as_float((m).w);               \
        const float xr = unpack_lo(p);                        \
        const float xi = unpack_hi(p);                        \
        aR = fmaf(cr, xr, fmaf(-ci, xi, aR));                 \
        aI = fmaf(cr, xi, fmaf(ci, xr, aI));                  \
    } while (0)

__global__ __launch_bounds__(256) void k_gather(
    const u32* __restrict__ x1p,
    const float* __restrict__ x_real, const float* __restrict__ x_imag,
    const float* __restrict__ weight, const float* __restrict__ bias,
    const int* __restrict__ offsets, const int4* __restrict__ meta,
    float* __restrict__ out_real, float* __restrict__ out_imag,
    int n_nodes)
{
    const int lane = threadIdx.x & 63;
    const int w = (blockIdx.x * blockDim.x + threadIdx.x) >> 6;
    const int nw = (gridDim.x * blockDim.x) >> 6;

    const float* __restrict__ W0 = weight;
    float w0c[F];
#pragma unroll
    for (int k = 0; k < F; ++k) w0c[k] = W0[k * F + lane];
    const float bf = bias[lane];

    for (int n = w; n < n_nodes; n += nw) {
        const int nu = __builtin_amdgcn_readfirstlane(n);
        const int beg = __builtin_amdgcn_readfirstlane(offsets[nu]);
        const int end = __builtin_amdgcn_readfirstlane(offsets[nu + 1]);

        float aR0 = 0.f, aI0 = 0.f, aR1 = 0.f, aI1 = 0.f;
        float aR2 = 0.f, aI2 = 0.f, aR3 = 0.f, aI3 = 0.f;

        int e = beg;
        for (; e + 4 <= end; e += 4) {
            const int4 m0 = meta[e + 0];
            const int4 m1 = meta[e + 1];
            const int4 m2 = meta[e + 2];
            const int4 m3 = meta[e + 3];
            const u32 p0 = x1p[(size_t)m0.x * F + lane];
            const u32 p1 = x1p[(size_t)m1.x * F + lane];
            const u32 p2 = x1p[(size_t)m2.x * F + lane];
            const u32 p3 = x1p[(size_t)m3.x * F + lane];
            APPLY(m0, p0, aR0, aI0);
            APPLY(m1, p1, aR1, aI1);
            APPLY(m2, p2, aR2, aI2);
            APPLY(m3, p3, aR3, aI3);
        }
        for (; e < end; ++e) {
            const int4 m = meta[e];
            const u32 p = x1p[(size_t)m.x * F + lane];
            APPLY(m, p, aR0, aI0);
        }

        const float4* __restrict__ xr4 = (const float4*)(x_real + (size_t)nu * F);
        const float4* __restrict__ xi4 = (const float4*)(x_imag + (size_t)nu * F);
        float gR = 0.f, gI = 0.f;
#pragma unroll
        for (int k4 = 0; k4 < F / 4; ++k4) {
            const float4 vr = xr4[k4];
            const float4 vi = xi4[k4];
            const float xr[4] = {vr.x, vr.y, vr.z, vr.w};
            const float xi[4] = {vi.x, vi.y, vi.z, vi.w};
#pragma unroll
            for (int j = 0; j < 4; ++j) {
                const int k = 4 * k4 + j;
                gR = fmaf(xr[j], w0c[k], gR);
                gI = fmaf(xi[j], w0c[k], gI);
            }
        }

        const size_t b = (size_t)nu * F + lane;
        out_real[b] = gR + bf + ((aR0 + aR1) + (aR2 + aR3));
        out_imag[b] = gI + bf + ((aI0 + aI1) + (aI2 + aI3));
    }
}

// ---------------------------------------------------------------------------
// Fallback (ws too small): atomic scatter from packed x1 + separate init.
// ---------------------------------------------------------------------------
__global__ __launch_bounds__(256) void k_init_out(
    const float* __restrict__ x_real, const float* __restrict__ x_imag,
    const float* __restrict__ weight, const float* __restrict__ bias,
    float* __restrict__ out_real, float* __restrict__ out_imag, int n_nodes)
{
    const int lane = threadIdx.x & 63;
    const int waveId = (blockIdx.x * blockDim.x + threadIdx.x) >> 6;
    const int nWaves = (gridDim.x * blockDim.x) >> 6;
    const float* __restrict__ W0 = weight;
    float w0c[F];
#pragma unroll
    for (int k = 0; k < F; ++k) w0c[k] = W0[k * F + lane];
    const float bf = bias[lane];
    for (int n = waveId; n < n_nodes; n += nWaves) {
        const int nu = __builtin_amdgcn_readfirstlane(n);
        const float4* __restrict__ xr4 = (const float4*)(x_real + (size_t)nu * F);
        const float4* __restrict__ xi4 = (const float4*)(x_imag + (size_t)nu * F);
        float gR = 0.f, gI = 0.f;
#pragma unroll
        for (int k4 = 0; k4 < F / 4; ++k4) {
            const float4 vr = xr4[k4];
            const float4 vi = xi4[k4];
            const float xr[4] = {vr.x, vr.y, vr.z, vr.w};
            const float xi[4] = {vi.x, vi.y, vi.z, vi.w};
#pragma unroll
            for (int j = 0; j < 4; ++j) {
                const int k = 4 * k4 + j;
                gR = fmaf(xr[j], w0c[k], gR);
                gI = fmaf(xi[j], w0c[k], gI);
            }
        }
        const size_t b = (size_t)nu * F + lane;
        out_real[b] = gR + bf;
        out_imag[b] = gI + bf;
    }
}

__global__ __launch_bounds__(256) void k_scatter(
    const u32* __restrict__ x1p, const int* __restrict__ edge_index,
    const float* __restrict__ norm_real, const float* __restrict__ norm_imag,
    float* __restrict__ out_real, float* __restrict__ out_imag, int n_edges)
{
    const long long gid = (long long)blockIdx.x * blockDim.x + threadIdx.x;
    const long long total = (long long)n_edges * 16;
    if (gid >= total) return;
    const int e = (int)(gid >> 4);
    const int c = (int)(gid & 15);
    const int s = edge_index[e];
    const int d = edge_index[n_edges + e];
    const float cr = norm_real[e];
    const float ci = norm_imag[e];
    const uint4 p4 = *(const uint4*)(x1p + (size_t)d * F + c * 4);
    const u32 pp[4] = {p4.x, p4.y, p4.z, p4.w};
    float* __restrict__ pr = out_real + (size_t)s * F + c * 4;
    float* __restrict__ pi = out_imag + (size_t)s * F + c * 4;
#pragma unroll
    for (int j = 0; j < 4; ++j) {
        const float xr = unpack_lo(pp[j]);
        const float xi = unpack_hi(pp[j]);
        unsafeAtomicAdd(pr + j, fmaf(cr, xr, -ci * xi));
        unsafeAtomicAdd(pi + j, fmaf(cr, xi, ci * xr));
    }
}

extern "C" void kernel_launch(void* const* d_in, const int* in_sizes, int n_in,
                              void* d_out, int out_size, void* d_ws, size_t ws_size,
                              hipStream_t stream) {
    const float* x_real     = (const float*)d_in[0];
    const float* x_imag     = (const float*)d_in[1];
    const float* weight     = (const float*)d_in[2];
    const float* bias       = (const float*)d_in[3];
    const float* norm_real  = (const float*)d_in[4];
    const float* norm_imag  = (const float*)d_in[5];
    const int*   edge_index = (const int*)d_in[6];

    const int n_nodes = in_sizes[0] / F;
    const int n_edges = in_sizes[4];

    float* out_real = (float*)d_out;
    float* out_imag = out_real + (size_t)n_nodes * F;

    // ws layout: [x1p][meta][offsets][cursor][partials]
    char* ws = (char*)d_ws;
    const size_t x1_bytes   = (size_t)n_nodes * F * sizeof(u32);
    const size_t meta_bytes = (size_t)n_edges * sizeof(int4);
    const size_t off_bytes  = (size_t)(n_nodes + 1) * sizeof(int);
    const size_t cur_bytes  = (size_t)n_nodes * sizeof(int);
    const size_t par_bytes  = 64 * sizeof(int);
    const size_t need = x1_bytes + meta_bytes + off_bytes + cur_bytes + par_bytes;

    u32*  x1p      = (u32*)ws;
    int4* meta     = (int4*)(ws + x1_bytes);
    int*  offsets  = (int*)(ws + x1_bytes + meta_bytes);
    int*  cursor   = (int*)(ws + x1_bytes + meta_bytes + off_bytes);
    int*  partials = (int*)(ws + x1_bytes + meta_bytes + off_bytes + cur_bytes);

    k_x1<<<2048, 256, 0, stream>>>(x_real, x_imag, weight, x1p, n_nodes);

    const int eblocks = (n_edges + 255) / 256;

    if (ws_size >= need) {
        const int sblocks = (n_nodes + SCAN_BLOCK * SCAN_ITEMS - 1) / (SCAN_BLOCK * SCAN_ITEMS); // 25 for 100k (<=64)
        hipMemsetAsync(cursor, 0, cur_bytes, stream);
        k_hist<<<eblocks, 256, 0, stream>>>(edge_index, cursor, n_edges);
        k_scan1<<<sblocks, SCAN_BLOCK, 0, stream>>>(cursor, offsets, partials, n_nodes);
        k_scan2<<<sblocks, SCAN_BLOCK, 0, stream>>>(offsets, partials, cursor, n_nodes, n_edges);
        k_place<<<eblocks, 256, 0, stream>>>(edge_index, norm_real, norm_imag,
                                             cursor, meta, n_edges);
        k_gather<<<2048, 256, 0, stream>>>(
            x1p, x_real, x_imag, weight, bias, offsets, meta,
            out_real, out_imag, n_nodes);
    } else {
        k_init_out<<<2048, 256, 0, stream>>>(
            x_real, x_imag, weight, bias, out_real, out_imag, n_nodes);
        const long long work = (long long)n_edges * 16;
        const int blocks = (int)((work + 255) / 256);
        k_scatter<<<blocks, 256, 0, stream>>>(
            x1p, edge_index, norm_real, norm_imag, out_real, out_imag, n_edges);
    }
}

// Round 5
// 388.460 us; speedup vs baseline: 7.1102x; 1.0183x over previous
//
#include <hip/hip_runtime.h>

#define F 64
typedef unsigned int u32;

#define SCAN_BLOCK 1024
#define SCAN_ITEMS 4   // elements per thread -> 4096 per block

// ---- bf16x2 pack/unpack (RNE) ----------------------------------------------
__device__ __forceinline__ u32 pack_bf16x2(float lo, float hi) {
    u32 a = __float_as_uint(lo);
    u32 b = __float_as_uint(hi);
    a = (a + 0x7fffu + ((a >> 16) & 1u)) >> 16;
    b = (b + 0x7fffu + ((b >> 16) & 1u)) >> 16;
    return a | (b << 16);
}
__device__ __forceinline__ float unpack_lo(u32 p) { return __uint_as_float(p << 16); }
__device__ __forceinline__ float unpack_hi(u32 p) { return __uint_as_float(p & 0xffff0000u); }

// ---------------------------------------------------------------------------
// k_pre: per-node dense init + edge histogram (fused).
//   initp[n][f] = pack_bf16( x_r@W0+b , x_i@W0+b )   (written into d_out region!)
//   x1p[n][f]   = pack_bf16( x_r@W1   , x_i@W1   )
//   counts[src[e]]++ for all edges (grid-stride tail)
// ---------------------------------------------------------------------------
__global__ __launch_bounds__(256) void k_pre(
    const float* __restrict__ x_real, const float* __restrict__ x_imag,
    const float* __restrict__ weight, const float* __restrict__ bias,
    u32* __restrict__ x1p, u32* __restrict__ initp,
    const int* __restrict__ edge_src, int* __restrict__ counts,
    int n_nodes, int n_edges)
{
    const int lane = threadIdx.x & 63;
    const int waveId = (blockIdx.x * blockDim.x + threadIdx.x) >> 6;
    const int nWaves = (gridDim.x * blockDim.x) >> 6;

    const float* __restrict__ W0 = weight;
    const float* __restrict__ W1 = weight + F * F;
    float w0c[F], w1c[F];
#pragma unroll
    for (int k = 0; k < F; ++k) {
        w0c[k] = W0[k * F + lane];
        w1c[k] = W1[k * F + lane];
    }
    const float bf = bias[lane];

    for (int n = waveId; n < n_nodes; n += nWaves) {
        const int nu = __builtin_amdgcn_readfirstlane(n);
        const float4* __restrict__ xr4 = (const float4*)(x_real + (size_t)nu * F);
        const float4* __restrict__ xi4 = (const float4*)(x_imag + (size_t)nu * F);
        float aR0 = 0.f, aI0 = 0.f, aR1 = 0.f, aI1 = 0.f;
#pragma unroll
        for (int k4 = 0; k4 < F / 4; ++k4) {
            const float4 vr = xr4[k4];
            const float4 vi = xi4[k4];
            const float xr[4] = {vr.x, vr.y, vr.z, vr.w};
            const float xi[4] = {vi.x, vi.y, vi.z, vi.w};
#pragma unroll
            for (int j = 0; j < 4; ++j) {
                const int k = 4 * k4 + j;
                aR0 = fmaf(xr[j], w0c[k], aR0);
                aI0 = fmaf(xi[j], w0c[k], aI0);
                aR1 = fmaf(xr[j], w1c[k], aR1);
                aI1 = fmaf(xi[j], w1c[k], aI1);
            }
        }
        const size_t b = (size_t)nu * F + lane;
        initp[b] = pack_bf16x2(aR0 + bf, aI0 + bf);
        x1p[b]   = pack_bf16x2(aR1, aI1);
    }

    // fused histogram
    const int tid = blockIdx.x * blockDim.x + threadIdx.x;
    const int nt = gridDim.x * blockDim.x;
    for (int e = tid; e < n_edges; e += nt) atomicAdd(&counts[edge_src[e]], 1);
}

// ---------------------------------------------------------------------------
// Scan pass 1: per-block exclusive prefix -> pre[], block totals -> partials[]
// ---------------------------------------------------------------------------
__global__ __launch_bounds__(1024) void k_scan1(
    const int* __restrict__ cnt, int* __restrict__ pre,
    int* __restrict__ partials, int n)
{
    __shared__ int wsum[16];
    const int t = threadIdx.x;
    const int lane = t & 63, wid = t >> 6;
    const int base = blockIdx.x * (SCAN_BLOCK * SCAN_ITEMS) + t * SCAN_ITEMS;

    int v[SCAN_ITEMS];
    int local = 0;
#pragma unroll
    for (int j = 0; j < SCAN_ITEMS; ++j) {
        const int idx = base + j;
        const int c = (idx < n) ? cnt[idx] : 0;
        v[j] = local;
        local += c;
    }
    int incl = local;
#pragma unroll
    for (int d = 1; d < 64; d <<= 1) {
        int x = __shfl_up(incl, d);
        if (lane >= d) incl += x;
    }
    if (lane == 63) wsum[wid] = incl;
    __syncthreads();
    if (wid == 0) {
        int s = (lane < 16) ? wsum[lane] : 0;
#pragma unroll
        for (int d = 1; d < 16; d <<= 1) {
            int x = __shfl_up(s, d);
            if (lane >= d) s += x;
        }
        if (lane < 16) wsum[lane] = s;
    }
    __syncthreads();
    const int texcl = (incl - local) + (wid ? wsum[wid - 1] : 0);
#pragma unroll
    for (int j = 0; j < SCAN_ITEMS; ++j) {
        const int idx = base + j;
        if (idx < n) pre[idx] = texcl + v[j];
    }
    if (t == SCAN_BLOCK - 1) partials[blockIdx.x] = texcl + local;
}

// Pass 2: add block offset; write final offsets + cursor. gridDim <= 64.
__global__ __launch_bounds__(1024) void k_scan2(
    int* __restrict__ pre, const int* __restrict__ partials,
    int* __restrict__ cursor, int n, int n_edges)
{
    __shared__ int s_off;
    const int t = threadIdx.x;
    if (t < 64) {
        int val = (t < blockIdx.x) ? partials[t] : 0;
#pragma unroll
        for (int d = 32; d > 0; d >>= 1) val += __shfl_down(val, d);
        if (t == 0) s_off = val;
    }
    __syncthreads();
    const int boff = s_off;
    const int base = blockIdx.x * (SCAN_BLOCK * SCAN_ITEMS) + t * SCAN_ITEMS;
#pragma unroll
    for (int j = 0; j < SCAN_ITEMS; ++j) {
        const int idx = base + j;
        if (idx < n) {
            const int o = boff + pre[idx];
            pre[idx] = o;
            cursor[idx] = o;
        }
    }
    if (blockIdx.x == 0 && t == 0) pre[n] = n_edges;
}

// ---------------------------------------------------------------------------
// Placement: meta2[pos] = {dst, pack_bf16(nr,ni)} sorted by src. 8 B/edge.
// ---------------------------------------------------------------------------
__global__ void k_place(const int* __restrict__ edge_index,
                        const float* __restrict__ nr, const float* __restrict__ ni,
                        int* __restrict__ cursor, int2* __restrict__ meta2, int n_edges) {
    int e = blockIdx.x * 256 + threadIdx.x;
    if (e >= n_edges) return;
    const int s = edge_index[e];
    const int pos = atomicAdd(&cursor[s], 1);
    int2 m;
    m.x = edge_index[n_edges + e];
    m.y = (int)pack_bf16x2(nr[e], ni[e]);
    meta2[pos] = m;
}

// ---------------------------------------------------------------------------
// Gather: one wave per node. Pure {meta -> gather -> FMA}; init from initp.
// ---------------------------------------------------------------------------
#define APPLY2(m, p, aR, aI)                                  \
    do {                                                      \
        const float cr = unpack_lo((u32)(m).y);               \
        const float ci = unpack_hi((u32)(m).y);               \
        const float xr = unpack_lo(p);                        \
        const float xi = unpack_hi(p);                        \
        aR = fmaf(cr, xr, fmaf(-ci, xi, aR));                 \
        aI = fmaf(cr, xi, fmaf(ci, xr, aI));                  \
    } while (0)

__global__ __launch_bounds__(256) void k_gather(
    const u32* __restrict__ x1p, const u32* __restrict__ initp,
    const int* __restrict__ offsets, const int2* __restrict__ meta2,
    float* __restrict__ out_real, float* __restrict__ out_imag,
    int n_nodes)
{
    const int lane = threadIdx.x & 63;
    const int w = (blockIdx.x * blockDim.x + threadIdx.x) >> 6;
    const int nw = (gridDim.x * blockDim.x) >> 6;

    for (int n = w; n < n_nodes; n += nw) {
        const int nu = __builtin_amdgcn_readfirstlane(n);
        const int beg = __builtin_amdgcn_readfirstlane(offsets[nu]);
        const int end = __builtin_amdgcn_readfirstlane(offsets[nu + 1]);

        float aR0 = 0.f, aI0 = 0.f, aR1 = 0.f, aI1 = 0.f;
        float aR2 = 0.f, aI2 = 0.f, aR3 = 0.f, aI3 = 0.f;

        int e = beg;
        for (; e + 8 <= end; e += 8) {
            const int2 m0 = meta2[e + 0];
            const int2 m1 = meta2[e + 1];
            const int2 m2 = meta2[e + 2];
            const int2 m3 = meta2[e + 3];
            const int2 m4 = meta2[e + 4];
            const int2 m5 = meta2[e + 5];
            const int2 m6 = meta2[e + 6];
            const int2 m7 = meta2[e + 7];
            const u32 p0 = x1p[(size_t)m0.x * F + lane];
            const u32 p1 = x1p[(size_t)m1.x * F + lane];
            const u32 p2 = x1p[(size_t)m2.x * F + lane];
            const u32 p3 = x1p[(size_t)m3.x * F + lane];
            const u32 p4 = x1p[(size_t)m4.x * F + lane];
            const u32 p5 = x1p[(size_t)m5.x * F + lane];
            const u32 p6 = x1p[(size_t)m6.x * F + lane];
            const u32 p7 = x1p[(size_t)m7.x * F + lane];
            APPLY2(m0, p0, aR0, aI0);
            APPLY2(m1, p1, aR1, aI1);
            APPLY2(m2, p2, aR2, aI2);
            APPLY2(m3, p3, aR3, aI3);
            APPLY2(m4, p4, aR0, aI0);
            APPLY2(m5, p5, aR1, aI1);
            APPLY2(m6, p6, aR2, aI2);
            APPLY2(m7, p7, aR3, aI3);
        }
        for (; e + 4 <= end; e += 4) {
            const int2 m0 = meta2[e + 0];
            const int2 m1 = meta2[e + 1];
            const int2 m2 = meta2[e + 2];
            const int2 m3 = meta2[e + 3];
            const u32 p0 = x1p[(size_t)m0.x * F + lane];
            const u32 p1 = x1p[(size_t)m1.x * F + lane];
            const u32 p2 = x1p[(size_t)m2.x * F + lane];
            const u32 p3 = x1p[(size_t)m3.x * F + lane];
            APPLY2(m0, p0, aR0, aI0);
            APPLY2(m1, p1, aR1, aI1);
            APPLY2(m2, p2, aR2, aI2);
            APPLY2(m3, p3, aR3, aI3);
        }
        for (; e < end; ++e) {
            const int2 m = meta2[e];
            const u32 p = x1p[(size_t)m.x * F + lane];
            APPLY2(m, p, aR0, aI0);
        }

        const size_t b = (size_t)nu * F + lane;
        const u32 iw = initp[b];   // aliases out_real[b]; read-before-write, same thread
        const float oR = unpack_lo(iw) + ((aR0 + aR1) + (aR2 + aR3));
        const float oI = unpack_hi(iw) + ((aI0 + aI1) + (aI2 + aI3));
        __builtin_nontemporal_store(oR, &out_real[b]);
        __builtin_nontemporal_store(oI, &out_imag[b]);
    }
}

// ---------------------------------------------------------------------------
// Fallback (ws too small): f32 init + atomic scatter from packed x1.
// ---------------------------------------------------------------------------
__global__ __launch_bounds__(256) void k_init_out(
    const float* __restrict__ x_real, const float* __restrict__ x_imag,
    const float* __restrict__ weight, const float* __restrict__ bias,
    float* __restrict__ out_real, float* __restrict__ out_imag, int n_nodes)
{
    const int lane = threadIdx.x & 63;
    const int waveId = (blockIdx.x * blockDim.x + threadIdx.x) >> 6;
    const int nWaves = (gridDim.x * blockDim.x) >> 6;
    const float* __restrict__ W0 = weight;
    float w0c[F];
#pragma unroll
    for (int k = 0; k < F; ++k) w0c[k] = W0[k * F + lane];
    const float bf = bias[lane];
    for (int n = waveId; n < n_nodes; n += nWaves) {
        const int nu = __builtin_amdgcn_readfirstlane(n);
        const float4* __restrict__ xr4 = (const float4*)(x_real + (size_t)nu * F);
        const float4* __restrict__ xi4 = (const float4*)(x_imag + (size_t)nu * F);
        float gR = 0.f, gI = 0.f;
#pragma unroll
        for (int k4 = 0; k4 < F / 4; ++k4) {
            const float4 vr = xr4[k4];
            const float4 vi = xi4[k4];
            const float xr[4] = {vr.x, vr.y, vr.z, vr.w};
            const float xi[4] = {vi.x, vi.y, vi.z, vi.w};
#pragma unroll
            for (int j = 0; j < 4; ++j) {
                const int k = 4 * k4 + j;
                gR = fmaf(xr[j], w0c[k], gR);
                gI = fmaf(xi[j], w0c[k], gI);
            }
        }
        const size_t b = (size_t)nu * F + lane;
        out_real[b] = gR + bf;
        out_imag[b] = gI + bf;
    }
}

__global__ __launch_bounds__(256) void k_scatter(
    const u32* __restrict__ x1p, const int* __restrict__ edge_index,
    const float* __restrict__ norm_real, const float* __restrict__ norm_imag,
    float* __restrict__ out_real, float* __restrict__ out_imag, int n_edges)
{
    const long long gid = (long long)blockIdx.x * blockDim.x + threadIdx.x;
    const long long total = (long long)n_edges * 16;
    if (gid >= total) return;
    const int e = (int)(gid >> 4);
    const int c = (int)(gid & 15);
    const int s = edge_index[e];
    const int d = edge_index[n_edges + e];
    const float cr = norm_real[e];
    const float ci = norm_imag[e];
    const uint4 p4 = *(const uint4*)(x1p + (size_t)d * F + c * 4);
    const u32 pp[4] = {p4.x, p4.y, p4.z, p4.w};
    float* __restrict__ pr = out_real + (size_t)s * F + c * 4;
    float* __restrict__ pi = out_imag + (size_t)s * F + c * 4;
#pragma unroll
    for (int j = 0; j < 4; ++j) {
        const float xr = unpack_lo(pp[j]);
        const float xi = unpack_hi(pp[j]);
        unsafeAtomicAdd(pr + j, fmaf(cr, xr, -ci * xi));
        unsafeAtomicAdd(pi + j, fmaf(cr, xi, ci * xr));
    }
}

extern "C" void kernel_launch(void* const* d_in, const int* in_sizes, int n_in,
                              void* d_out, int out_size, void* d_ws, size_t ws_size,
                              hipStream_t stream) {
    const float* x_real     = (const float*)d_in[0];
    const float* x_imag     = (const float*)d_in[1];
    const float* weight     = (const float*)d_in[2];
    const float* bias       = (const float*)d_in[3];
    const float* norm_real  = (const float*)d_in[4];
    const float* norm_imag  = (const float*)d_in[5];
    const int*   edge_index = (const int*)d_in[6];

    const int n_nodes = in_sizes[0] / F;
    const int n_edges = in_sizes[4];

    float* out_real = (float*)d_out;
    float* out_imag = out_real + (size_t)n_nodes * F;
    u32*   initp    = (u32*)d_out;   // packed bf16 init, overwritten by gather

    // ws layout: [x1p][meta2][offsets][cursor][partials]
    char* ws = (char*)d_ws;
    const size_t x1_bytes   = (size_t)n_nodes * F * sizeof(u32);   // 25.6 MB
    const size_t meta_bytes = (size_t)n_edges * sizeof(int2);      // 12.8 MB
    const size_t off_bytes  = (size_t)(n_nodes + 1) * sizeof(int);
    const size_t cur_bytes  = (size_t)n_nodes * sizeof(int);
    const size_t par_bytes  = 64 * sizeof(int);
    const size_t need = x1_bytes + meta_bytes + off_bytes + cur_bytes + par_bytes;

    u32*  x1p      = (u32*)ws;
    int2* meta2    = (int2*)(ws + x1_bytes);
    int*  offsets  = (int*)(ws + x1_bytes + meta_bytes);
    int*  cursor   = (int*)(ws + x1_bytes + meta_bytes + off_bytes);
    int*  partials = (int*)(ws + x1_bytes + meta_bytes + off_bytes + cur_bytes);

    const int eblocks = (n_edges + 255) / 256;

    if (ws_size >= need) {
        hipMemsetAsync(cursor, 0, cur_bytes, stream);
        k_pre<<<2048, 256, 0, stream>>>(
            x_real, x_imag, weight, bias, x1p, initp, edge_index, cursor,
            n_nodes, n_edges);
        const int sblocks = (n_nodes + SCAN_BLOCK * SCAN_ITEMS - 1) / (SCAN_BLOCK * SCAN_ITEMS);
        k_scan1<<<sblocks, SCAN_BLOCK, 0, stream>>>(cursor, offsets, partials, n_nodes);
        k_scan2<<<sblocks, SCAN_BLOCK, 0, stream>>>(offsets, partials, cursor, n_nodes, n_edges);
        k_place<<<eblocks, 256, 0, stream>>>(edge_index, norm_real, norm_imag,
                                             cursor, meta2, n_edges);
        k_gather<<<2048, 256, 0, stream>>>(
            x1p, initp, offsets, meta2, out_real, out_imag, n_nodes);
    } else {
        // Fallback: only x1p needed in ws.
        k_x1_fallback:;
        k_init_out<<<2048, 256, 0, stream>>>(
            x_real, x_imag, weight, bias, out_real, out_imag, n_nodes);
        // build x1p (reuse k_pre without hist side effects would clobber d_out init;
        // use a dedicated minimal producer)
        // note: k_pre writes initp into d_out, which k_init_out already wrote as f32;
        // so for fallback we must NOT run k_pre. Build x1p via k_scatter's producer:
        // simplest: run k_pre into ws-only x1p with initp pointed at x1p? Not safe.
        // Instead reuse k_init-style kernel for x1p:
        // (declared below via lambda-less separate kernel)
        extern __global__ void k_x1_only(const float*, const float*, const float*, u32*, int);
        k_x1_only<<<2048, 256, 0, stream>>>(x_real, x_imag, weight, x1p, n_nodes);
        const long long work = (long long)n_edges * 16;
        const int blocks = (int)((work + 255) / 256);
        k_scatter<<<blocks, 256, 0, stream>>>(
            x1p, edge_index, norm_real, norm_imag, out_real, out_imag, n_edges);
    }
}

// Fallback x1 producer (W1 only).
__global__ __launch_bounds__(256) void k_x1_only(
    const float* __restrict__ x_real, const float* __restrict__ x_imag,
    const float* __restrict__ weight, u32* __restrict__ x1p, int n_nodes)
{
    const int lane = threadIdx.x & 63;
    const int waveId = (blockIdx.x * blockDim.x + threadIdx.x) >> 6;
    const int nWaves = (gridDim.x * blockDim.x) >> 6;
    const float* __restrict__ W1 = weight + F * F;
    float w1c[F];
#pragma unroll
    for (int k = 0; k < F; ++k) w1c[k] = W1[k * F + lane];
    for (int n = waveId; n < n_nodes; n += nWaves) {
        const int nu = __builtin_amdgcn_readfirstlane(n);
        const float4* __restrict__ xr4 = (const float4*)(x_real + (size_t)nu * F);
        const float4* __restrict__ xi4 = (const float4*)(x_imag + (size_t)nu * F);
        float aR = 0.f, aI = 0.f;
#pragma unroll
        for (int k4 = 0; k4 < F / 4; ++k4) {
            const float4 vr = xr4[k4];
            const float4 vi = xi4[k4];
            const float xr[4] = {vr.x, vr.y, vr.z, vr.w};
            const float xi[4] = {vi.x, vi.y, vi.z, vi.w};
#pragma unroll
            for (int j = 0; j < 4; ++j) {
                const int k = 4 * k4 + j;
                aR = fmaf(xr[j], w1c[k], aR);
                aI = fmaf(xi[j], w1c[k], aI);
            }
        }
        x1p[(size_t)nu * F + lane] = pack_bf16x2(aR, aI);
    }
}